// Round 7
// baseline (163.099 us; speedup 1.0000x reference)
//
#include <hip/hip_runtime.h>
#include <cfloat>
#include <cmath>

#define NP 10000
#define NG 1000
#define NC 80
#define LMAX 6
#define NCH 4
#define CHSZ (NP / NCH)     // 2500
#define CMAIN 9             // 9*256 = 2304
#define CTAIL 196           // 2304 + 196 = 2500

#define S_MULTI 12
#define S_BODY  16
#define RI_BIG  0x3fffffff
#define KMAX    0xFFFFFFFFFFFFFFFFull

// packkey(50.0f,0): strong (inb) costs < ~28, non-strong >= ~59 (validated
// across rounds at 5000/10000 chunk sizes; the gate argument is chunk-size-
// independent: if the chunk's 5th-smallest candidate key >= TKEY we cannot
// prove the candidate set covers the chunk's true top-5 -> exact chunk scan.
#define TKEY    0xC248000000000000ull

// per-wave candidate region (LDS ints, aliased over s_iv): 4 waves x 448.
// Per-wave expected hits ~25 (4% x 64 x 10), big-gt ~60; 448 is ample.
#define WCAP    448

__device__ __forceinline__ bool lexless(float av, int ai, float bv, int bi) {
    return (av < bv) || (av == bv && ai < bi);
}

// float -> order-preserving u32 (no NaNs in this data), packed with index.
// ascending u64 order == lexicographic (value asc, index asc).
__device__ __forceinline__ unsigned long long packkey(float v, int idx) {
    unsigned u = __float_as_uint(v);
    u ^= (unsigned)(((int)u) >> 31) | 0x80000000u;
    return ((unsigned long long)u << 32) | (unsigned)idx;
}
__device__ __forceinline__ int keyidx(unsigned long long k) {
    return (int)(unsigned)(k & 0xFFFFFFFFu);
}

// Exact sequential +1e5 inflation (reference adds 1e5 once per loop iter).
__device__ __forceinline__ float inflate(float c, int k) {
    for (int q = 0; q < k; q++) c += 100000.0f;
    return c;
}

// Per-pair cost+iou from precomputed tables. Contraction OFF so every kernel
// that recomputes cost(i,j) agrees bit-exactly.
__device__ __forceinline__ void cost_iou(float4 p, float4 pn, float4 pi,
        float4 g, float4 cb, float4 Gn, float ga, float clsv,
        float& cc_out, float& iou_out) {
#pragma clang fp contract(off)
    float wx = fminf(p.z, g.z) - fmaxf(p.x, g.x); wx = fmaxf(wx, 0.0f);
    float wy = fminf(p.w, g.w) - fmaxf(p.y, g.y); wy = fmaxf(wy, 0.0f);
    float inter = wx * wy;
    float uni = pi.z + ga - inter;
    float iou = inter / fmaxf(uni, 1e-12f);
    float ex = fmaxf(p.z, g.z) - fminf(p.x, g.x); ex = fmaxf(ex, 0.0f);
    float ey = fmaxf(p.w, g.w) - fminf(p.y, g.y); ey = fmaxf(ey, 0.0f);
    float enc = ex * ey;
    float giou = iou - (enc - uni) / fmaxf(enc, 1e-12f);
    float l1 = ((fabsf(pn.x - Gn.x) + fabsf(pn.y - Gn.y))
                + fabsf(pn.z - Gn.z)) + fabsf(pn.w - Gn.w);
    float cc = clsv + l1 * 5.0f;
    cc = cc + (-giou * 2.0f);
    bool inb = (pi.x > g.x && pi.x < g.z && pi.y > g.y && pi.y < g.w);
    bool inc = (pi.x > cb.x && pi.x < cb.z && pi.y > cb.y && pi.y < cb.w);
    cc = cc + ((inb && inc) ? 0.0f : 100.0f);
    cc = cc + pi.w;
    cc_out = cc; iou_out = iou;
}

// Proven per-thread sorted top-5 insertion (static indices after unroll).
// Per-thread top-5 is ALWAYS sufficient for the block top-5.
__device__ __forceinline__ void ins5k(unsigned long long* kv,
        unsigned long long key) {
    if (key < kv[4]) {
        kv[4] = key;
#pragma unroll
        for (int t = 4; t > 0; t--)
            if (kv[t] < kv[t-1]) { unsigned long long tv = kv[t]; kv[t] = kv[t-1]; kv[t-1] = tv; }
    }
}
__device__ __forceinline__ void ins5i(float* iv, float iou) {
    if (iou > iv[4]) {
        iv[4] = iou;
#pragma unroll
        for (int t = 4; t > 0; t--)
            if (iv[t] > iv[t-1]) { float tv = iv[t]; iv[t] = iv[t-1]; iv[t-1] = tv; }
    }
}

// ---------------------------------------------------------------------------
// Fused prep (verbatim R1). Block ranges:
//  [0,40): init state; [40,197): cls table; [197,201): per-gt tables;
//  [201,2701): wave-per-pred validity + per-pred tables
// ---------------------------------------------------------------------------
#define CLS_TI 64
#define PB_CLS0 40
#define PB_G0   197
#define PB_V0   201
__global__ __launch_bounds__(256) void k_prep(const float* __restrict__ logits,
        const float* __restrict__ pb, const float* __restrict__ gb,
        const int* __restrict__ imgw, const int* __restrict__ imgh,
        float* __restrict__ clsval, float4* __restrict__ pnorm,
        float4* __restrict__ pinfo, float4* __restrict__ gcb,
        float4* __restrict__ gnm, float* __restrict__ gar,
        int* rowcnt, int* rowfirst, int* rowiter, int* prior, int* priorcol,
        int* colsum, int* scal)
{
    __shared__ float sl[CLS_TI * (NC + 1)];
    int b = blockIdx.x;
    if (b < PB_CLS0) {
        int i = b * 256 + threadIdx.x;
        if (i < NP) {
            rowcnt[i] = 0; rowfirst[i] = 0x7fffffff; rowiter[i] = RI_BIG;
            prior[i] = 0; priorcol[i] = 0;
        }
        if (i < NG) colsum[i] = 0;
        if (i < 32) scal[i] = 0;
    } else if (b < PB_G0) {
        int i0 = (b - PB_CLS0) * CLS_TI;
        bool full = (i0 + CLS_TI) <= NP;
        if (full) {
            const float* src = logits + (size_t)i0 * NC;
            for (int e = threadIdx.x; e < CLS_TI * NC; e += 256) {
                int di = e / NC, c = e - di * NC;
                sl[di * (NC + 1) + c] = src[e];
            }
        } else {
            for (int e = threadIdx.x; e < CLS_TI * NC; e += 256) {
                int di = e / NC, c = e - di * NC;
                int i = i0 + di;
                sl[di * (NC + 1) + c] = (i < NP) ? logits[(size_t)i * NC + c] : 0.0f;
            }
        }
        __syncthreads();
        for (int e = threadIdx.x; e < CLS_TI * NC; e += 256) {
            int c = e >> 6, di = e & 63;
            int i = i0 + di;
            if (i >= NP) continue;
            float x = sl[di * (NC + 1) + c];
            float p = 1.0f / (1.0f + expf(-x));
            float neg = -log1pf(-(p - 1e-12f)) * 0.75f * (p * p);
            float om = 1.0f - p;
            float pos = -logf(p + 1e-12f) * 0.25f * (om * om);
            clsval[(size_t)c * NP + i] = (pos - neg) * 2.0f;   // * CLS_W
        }
    } else if (b < PB_V0) {
#pragma clang fp contract(off)
        int j = (b - PB_G0) * 256 + threadIdx.x;
        if (j < NG) {
            float fw = (float)imgw[0], fh = (float)imgh[0];
            float4 g = ((const float4*)gb)[j];
            float gcx = (g.x + g.z) * 0.5f, gcy = (g.y + g.w) * 0.5f;
            float gw = g.z - g.x, gh = g.w - g.y;
            float4 cb; cb.x = gcx - 2.5f * gw; cb.y = gcy - 2.5f * gh;
            cb.z = gcx + 2.5f * gw; cb.w = gcy + 2.5f * gh;
            gcb[j] = cb;
            float4 Gn; Gn.x = g.x / fw; Gn.y = g.y / fh; Gn.z = g.z / fw; Gn.w = g.w / fh;
            gnm[j] = Gn;
            gar[j] = (g.z - g.x) * (g.w - g.y);
        }
    } else {
#pragma clang fp contract(off)
        int wave = threadIdx.x >> 6;
        int lane = threadIdx.x & 63;
        int i = (b - PB_V0) * 4 + wave;
        if (i >= NP) return;
        float4 p = ((const float4*)pb)[i];
        float pcx = (p.x + p.z) * 0.5f, pcy = (p.y + p.w) * 0.5f;
        int vb = 0, vc = 0;
        const float4* gb4 = (const float4*)gb;
        // valid = any(inb) | any(inc): wave-level early exit as soon as
        // the disjunction is already established (~93% exit after 1 stride).
        for (int jb = 0; jb < NG; jb += 64) {
            int j = jb + lane;
            if (j < NG) {
                float4 g = gb4[j];
                vb |= (pcx > g.x && pcx < g.z && pcy > g.y && pcy < g.w) ? 1 : 0;
                float gcx = (g.x + g.z) * 0.5f, gcy = (g.y + g.w) * 0.5f;
                float gw = g.z - g.x, gh = g.w - g.y;
                vc |= (pcx > gcx - 2.5f * gw && pcx < gcx + 2.5f * gw &&
                       pcy > gcy - 2.5f * gh && pcy < gcy + 2.5f * gh) ? 1 : 0;
            }
            if (__any(vb | vc)) break;
        }
        int any = __any(vb | vc) ? 1 : 0;
        if (lane == 0) {
            float fw = (float)imgw[0], fh = (float)imgh[0];
            float4 pn; pn.x = p.x / fw; pn.y = p.y / fh; pn.z = p.z / fw; pn.w = p.w / fh;
            pnorm[i] = pn;
            float4 pi4; pi4.x = pcx; pi4.y = pcy;
            pi4.z = (p.z - p.x) * (p.w - p.y);
            pi4.w = any ? 0.0f : 10000.0f;
            pinfo[i] = pi4;
        }
    }
}

// stride-7 LDS top-5 merge tree (proven). All threads must call (barriers).
__device__ __forceinline__ void tree57(unsigned long long* s_k, float* s_iv,
        int tid) {
    for (int w = 128; w > 0; w >>= 1) {
        if (tid < w) {
            int a = tid * 7, bb = (tid + w) * 7;
            unsigned long long ok[5]; float og[5];
            int pa = a, pbp = bb;
#pragma unroll
            for (int t = 0; t < 5; t++) {
                unsigned long long A = s_k[pa], B = s_k[pbp];
                if (A <= B) { ok[t] = A; pa++; } else { ok[t] = B; pbp++; }
            }
            int qa = a, qb = bb;
#pragma unroll
            for (int t = 0; t < 5; t++) {
                float A = s_iv[qa], B = s_iv[qb];
                if (A >= B) { og[t] = A; qa++; } else { og[t] = B; qb++; }
            }
#pragma unroll
            for (int t = 0; t < 5; t++) { s_k[a+t] = ok[t]; s_iv[a+t] = og[t]; }
        }
        __syncthreads();
    }
}

// ---------------------------------------------------------------------------
// k_cost2: block (gt j, quarter-chunk c). R6's atomic-free per-wave
// compaction + R2-proven gate flow, at NCH=4 (measured scaling law R6->R1:
// time tracks phase-1 chain length / block parallelism; 4000 blocks x 10
// iterations is 4x parallelism + 1/4 chain vs R6).
//  Phase 1: cheap overlap scan (overlap <=> iou > 0 exactly; superset of the
//    strong set). Per-wave private LDS region, wave-uniform register cursor
//    (no LDS atomics, no shfl). List order irrelevant (keys embed index).
//  Phase 2: dense cost_iou over the 4 regions; per-thread 5-deep insertion;
//    proven stride-7 tree merge. IoU pads 0.0f == exact non-candidate iou.
//  Gates: any-wave-overflow -> primary chunk scan; s_k[4] >= TKEY -> redo
//    chunk scan (covers cnt<5: KMAX >= TKEY).
//  Output: sorted 5-list (pck/piv) per (gt, chunk) for the 4-way merge.
// ---------------------------------------------------------------------------
__global__ __launch_bounds__(256) void k_cost2(
        const float* __restrict__ pb, const float* __restrict__ gb,
        const int* __restrict__ glab, const float* __restrict__ clsval,
        const float4* __restrict__ pnorm, const float4* __restrict__ pinfo,
        const float4* __restrict__ gcb, const float4* __restrict__ gnm,
        const float* __restrict__ gar,
        unsigned long long* __restrict__ pck, float* __restrict__ piv)
{
    __shared__ unsigned long long s_k[256 * 7];
    __shared__ float s_iv[256 * 7];
    __shared__ int s_wcnt[4];
    int* s_list = (int*)s_iv;     // aliased; fully consumed before s_iv writes

    int j = blockIdx.x >> 2;
    int c = blockIdx.x & 3;
    int tid = threadIdx.x;
    int wid = tid >> 6;
    int ln  = tid & 63;
    float4 g  = ((const float4*)gb)[j];
    float4 cb = gcb[j];
    float4 Gn = gnm[j];
    float  ga = gar[j];
    const float* clscol = clsval + (size_t)glab[j] * NP;
    const float4* pb4 = (const float4*)pb;
    int base_i = c * CHSZ;

    // ---- phase 1: cheap overlap scan, atomic-free per-wave compaction ----
    int wbase = 0;                       // wave-uniform cursor
    for (int k = 0; k <= CMAIN; k++) {
        if (k == CMAIN && tid >= CTAIL) break;
        int i = base_i + tid + k * 256;
        float4 p = pb4[i];
        bool o = (p.z > g.x) & (g.z > p.x) & (p.w > g.y) & (g.w > p.y);
        unsigned long long m = __ballot(o ? 1 : 0);
        if (o) {
            int slot = wbase + __popcll(m & ((1ull << ln) - 1ull));
            if (slot < WCAP) s_list[wid * WCAP + slot] = i;
        }
        wbase += __popcll(m);
    }
    if (ln == 0) s_wcnt[wid] = wbase;
    __syncthreads();
    int c0 = s_wcnt[0], c1 = s_wcnt[1], c2 = s_wcnt[2], c3 = s_wcnt[3];
    bool overflow = (c0 > WCAP) | (c1 > WCAP) | (c2 > WCAP) | (c3 > WCAP);

    unsigned long long kv[5]; float iv[5];
#pragma unroll
    for (int t = 0; t < 5; t++) { kv[t] = KMAX; iv[t] = overflow ? -1.0f : 0.0f; }

    if (!overflow) {
        // ---- phase 2: dense evals over the 4 wave regions ----
        for (int q = tid; q < c0; q += 256) {
            int i = s_list[q];
            float cc, iou;
            cost_iou(pb4[i], pnorm[i], pinfo[i], g, cb, Gn, ga, clscol[i], cc, iou);
            ins5k(kv, packkey(cc, i)); ins5i(iv, iou);
        }
        for (int q = tid; q < c1; q += 256) {
            int i = s_list[WCAP + q];
            float cc, iou;
            cost_iou(pb4[i], pnorm[i], pinfo[i], g, cb, Gn, ga, clscol[i], cc, iou);
            ins5k(kv, packkey(cc, i)); ins5i(iv, iou);
        }
        for (int q = tid; q < c2; q += 256) {
            int i = s_list[2 * WCAP + q];
            float cc, iou;
            cost_iou(pb4[i], pnorm[i], pinfo[i], g, cb, Gn, ga, clscol[i], cc, iou);
            ins5k(kv, packkey(cc, i)); ins5i(iv, iou);
        }
        for (int q = tid; q < c3; q += 256) {
            int i = s_list[3 * WCAP + q];
            float cc, iou;
            cost_iou(pb4[i], pnorm[i], pinfo[i], g, cb, Gn, ga, clscol[i], cc, iou);
            ins5k(kv, packkey(cc, i)); ins5i(iv, iou);
        }
    } else {
        // primary exact chunk scan (rare: a wave saw > WCAP hits)
        for (int k = 0; k <= CMAIN; k++) {
            if (k == CMAIN && tid >= CTAIL) break;
            int i = base_i + tid + k * 256;
            float cc, iou;
            cost_iou(pb4[i], pnorm[i], pinfo[i], g, cb, Gn, ga, clscol[i], cc, iou);
            ins5k(kv, packkey(cc, i)); ins5i(iv, iou);
        }
    }
    __syncthreads();              // list consumed; s_iv reusable

    int base = tid * 7;
#pragma unroll
    for (int t = 0; t < 5; t++) { s_k[base+t] = kv[t]; s_iv[base+t] = iv[t]; }
    s_k[base+5] = KMAX; s_iv[base+5] = -2.0f;
    __syncthreads();
    tree57(s_k, s_iv, tid);

    // gate: block-uniform read of merged 5th key (covers cnt<5: KMAX>=TKEY)
    bool redo = !overflow && (s_k[4] >= TKEY);
    __syncthreads();            // everyone has read s_k[4] before any rewrite

    if (redo) {
#pragma unroll
        for (int t = 0; t < 5; t++) { kv[t] = KMAX; iv[t] = -1.0f; }
        for (int k = 0; k <= CMAIN; k++) {
            if (k == CMAIN && tid >= CTAIL) break;
            int i = base_i + tid + k * 256;
            float cc, iou;
            cost_iou(pb4[i], pnorm[i], pinfo[i], g, cb, Gn, ga, clscol[i], cc, iou);
            ins5k(kv, packkey(cc, i)); ins5i(iv, iou);
        }
#pragma unroll
        for (int t = 0; t < 5; t++) { s_k[base+t] = kv[t]; s_iv[base+t] = iv[t]; }
        s_k[base+5] = KMAX; s_iv[base+5] = -2.0f;
        __syncthreads();
        tree57(s_k, s_iv, tid);
    }

    if (tid == 0) {
        int ob = blockIdx.x * 5;
#pragma unroll
        for (int t = 0; t < 5; t++) { pck[ob + t] = s_k[t]; piv[ob + t] = s_iv[t]; }
    }
}

// ---------------------------------------------------------------------------
// Merge partials: thread per gt. Exact 4-way merge of sorted 5-lists
// (structurally identical to R1's proven 2-way merge; keys unique -> strict
// min-selection deterministic; iou max-merge multiset-correct, descending
// sum order == reference's sorted-top-5 sum -> bit-exact dk).
// Stores merged top-5 indices, dk, row atomics.
// ---------------------------------------------------------------------------
__global__ __launch_bounds__(256) void k_costmerge(
        const unsigned long long* __restrict__ pck, const float* __restrict__ piv,
        int* __restrict__ rowcnt, int* __restrict__ rowfirst,
        int* __restrict__ rowiter, int* __restrict__ top5,
        int* __restrict__ dkarr)
{
    int j = blockIdx.x * 256 + threadIdx.x;
    if (j >= NG) return;
    int base = j * NCH * 5;
    int h0 = 0, h1 = 0, h2 = 0, h3 = 0;
    int besti[5];
#pragma unroll
    for (int r = 0; r < 5; r++) {
        unsigned long long v0 = (h0 < 5) ? pck[base + h0]      : KMAX;
        unsigned long long v1 = (h1 < 5) ? pck[base + 5 + h1]  : KMAX;
        unsigned long long v2 = (h2 < 5) ? pck[base + 10 + h2] : KMAX;
        unsigned long long v3 = (h3 < 5) ? pck[base + 15 + h3] : KMAX;
        unsigned long long best = v0; int sel = 0;
        if (v1 < best) { best = v1; sel = 1; }
        if (v2 < best) { best = v2; sel = 2; }
        if (v3 < best) { best = v3; sel = 3; }
        besti[r] = keyidx(best);
        h0 += (sel == 0); h1 += (sel == 1); h2 += (sel == 2); h3 += (sel == 3);
    }
    int g0 = 0, g1 = 0, g2 = 0, g3 = 0;
    float ivm[5];
#pragma unroll
    for (int r = 0; r < 5; r++) {
        float w0 = (g0 < 5) ? piv[base + g0]      : -2.0f;
        float w1 = (g1 < 5) ? piv[base + 5 + g1]  : -2.0f;
        float w2 = (g2 < 5) ? piv[base + 10 + g2] : -2.0f;
        float w3 = (g3 < 5) ? piv[base + 15 + g3] : -2.0f;
        float best = w0; int sel = 0;
        if (w1 > best) { best = w1; sel = 1; }
        if (w2 > best) { best = w2; sel = 2; }
        if (w3 > best) { best = w3; sel = 3; }
        ivm[r] = best;
        g0 += (sel == 0); g1 += (sel == 1); g2 += (sel == 2); g3 += (sel == 3);
    }
    float s = (((ivm[0] + ivm[1]) + ivm[2]) + ivm[3]) + ivm[4];
    int dk = (int)s;                 // astype(int32): truncation
    if (dk < 1) dk = 1;
    dkarr[j] = dk;
#pragma unroll
    for (int r = 0; r < 5; r++) top5[j * 5 + r] = besti[r];
    for (int t = 0; t < dk; t++) {
        int r = besti[t];
        atomicAdd(&rowcnt[r], 1);
        atomicMin(&rowfirst[r], j);
        atomicMin(&rowiter[r], -1);   // initially matched
    }
}

// ---------------------------------------------------------------------------
// Fused prior-detect + pfix + surv (verbatim R1).
// ---------------------------------------------------------------------------
__global__ __launch_bounds__(256) void k_pfixsurv(const float* __restrict__ pb,
        const float* __restrict__ gb, const int* __restrict__ glab,
        const float* __restrict__ clsval,
        const float4* __restrict__ pnorm, const float4* __restrict__ pinfo,
        const float4* __restrict__ gcb, const float4* __restrict__ gnm,
        const float* __restrict__ gar,
        int* __restrict__ prior, int* __restrict__ priorcol,
        int* __restrict__ colsum,
        const int* __restrict__ rowcnt, const int* __restrict__ top5,
        const int* __restrict__ dkarr)
{
    int b = blockIdx.x;
    int tid = threadIdx.x;
    if (b >= 2500) {
        int j = (b - 2500) * 256 + tid;
        if (j >= NG) return;
        int c = 0;
        int dk = dkarr[j];
        for (int t = 0; t < dk; t++) if (rowcnt[top5[j * 5 + t]] == 1) c++;
        if (c) atomicAdd(&colsum[j], c);
        return;
    }
    __shared__ float rv[256]; __shared__ int ri[256];
    for (int q = 0; q < 4; q++) {
        int row = b * 4 + q;
        if (rowcnt[row] <= 1) continue;      // uniform across block
        if (tid == 0) prior[row] = 1;
        float4 p = ((const float4*)pb)[row];
        float4 pn = pnorm[row];
        float4 pi4 = pinfo[row];
        float best = FLT_MAX; int bj = 0x7fffffff;
        for (int j = tid; j < NG; j += 256) {
            float cc, iou;
            cost_iou(p, pn, pi4, ((const float4*)gb)[j], gcb[j], gnm[j], gar[j],
                     clsval[(size_t)glab[j] * NP + row], cc, iou);
            if (lexless(cc, j, best, bj)) { best = cc; bj = j; }
        }
        rv[tid] = best; ri[tid] = bj; __syncthreads();
        for (int w = 128; w > 0; w >>= 1) {
            if (tid < w) {
                float ov = rv[tid + w]; int oi = ri[tid + w];
                if (lexless(ov, oi, rv[tid], ri[tid])) { rv[tid] = ov; ri[tid] = oi; }
            }
            __syncthreads();
        }
        if (tid == 0) {
            priorcol[row] = ri[0];
            atomicAdd(&colsum[ri[0]], 1);
        }
        __syncthreads();
    }
}

// ---------------------------------------------------------------------------
// iterB (verbatim R1): block per column; active iff colsum[j]==0.
// ---------------------------------------------------------------------------
__global__ __launch_bounds__(256) void k_iterB(const float* __restrict__ pb,
        const float* __restrict__ gb, const int* __restrict__ glab,
        const float* __restrict__ clsval,
        const float4* __restrict__ pnorm, const float4* __restrict__ pinfo,
        const float4* __restrict__ gcb, const float4* __restrict__ gnm,
        const float* __restrict__ gar, const int* __restrict__ top5,
        int* __restrict__ rowiter, int* __restrict__ rowcnt,
        int* __restrict__ rowfirst, int* __restrict__ colsum,
        int* __restrict__ scal, int t)
{
    int j = blockIdx.x;
    if (colsum[j] != 0) return;
    int tid = threadIdx.x;
    if (tid == 0) scal[S_BODY + t] = 1;

    __shared__ int s_pos;
    if (tid == 0) {
        int pos = -1;
        for (int r = 0; r < 5; r++) {
            int i = top5[j * 5 + r];
            if (rowiter[i] >= t) { pos = i; break; }
        }
        s_pos = pos;
    }
    __syncthreads();
    int pos = s_pos;

    if (pos < 0) {
        // fallback: full argmin over uninflated rows
        float4 g  = ((const float4*)gb)[j];
        float4 cb = gcb[j];
        float4 Gn = gnm[j];
        float  ga = gar[j];
        const float* clscol = clsval + (size_t)glab[j] * NP;
        const float4* pb4 = (const float4*)pb;
        __shared__ float rv[256]; __shared__ int ri[256];
        float best = FLT_MAX; int bi = 0x7fffffff;
        for (int i = tid; i < NP; i += 256) {
            if (rowiter[i] < t) continue;
            float cc, iou;
            cost_iou(pb4[i], pnorm[i], pinfo[i], g, cb, Gn, ga, clscol[i], cc, iou);
            if (lexless(cc, i, best, bi)) { best = cc; bi = i; }
        }
        rv[tid] = best; ri[tid] = bi; __syncthreads();
        for (int w = 128; w > 0; w >>= 1) {
            if (tid < w) {
                float ov = rv[tid + w]; int oi = ri[tid + w];
                if (lexless(ov, oi, rv[tid], ri[tid])) { rv[tid] = ov; ri[tid] = oi; }
            }
            __syncthreads();
        }
        pos = ri[0];
    }

    if (tid == 0) {
        colsum[j] = 1;
        int old = atomicAdd(&rowcnt[pos], 1);
        if (old >= 1) scal[S_MULTI] = 1;
        atomicMin(&rowfirst[pos], j);
        atomicMin(&rowiter[pos], t);
    }
}

// ---------------------------------------------------------------------------
// iterC (verbatim R1): iff body ran at t && anymulti: prior rows (4/block)
// re-argmin their inflated cost (exact sequential +1e5).
// ---------------------------------------------------------------------------
__global__ __launch_bounds__(256) void k_iterC(const float* __restrict__ pb,
        const float* __restrict__ gb, const int* __restrict__ glab,
        const float* __restrict__ clsval,
        const float4* __restrict__ pnorm, const float4* __restrict__ pinfo,
        const float4* __restrict__ gcb, const float4* __restrict__ gnm,
        const float* __restrict__ gar,
        const int* __restrict__ prior, const int* __restrict__ rowiter,
        int* __restrict__ priorcol, int* __restrict__ colsum,
        int* __restrict__ scal, int t)
{
    if (scal[S_BODY + t] == 0 || scal[S_MULTI] == 0) return;
    int b = blockIdx.x;
    int tid = threadIdx.x;
    __shared__ float rv[256]; __shared__ int ri[256];
    for (int q = 0; q < 4; q++) {
        int row = b * 4 + q;
        if (!prior[row]) continue;           // uniform across block
        int k = t - rowiter[row]; if (k < 0) k = 0;   // prior rows: -1 -> t+1
        float4 p = ((const float4*)pb)[row];
        float4 pn = pnorm[row];
        float4 pi4 = pinfo[row];
        float best = FLT_MAX; int bj = 0x7fffffff;
        for (int j = tid; j < NG; j += 256) {
            float cc, iou;
            cost_iou(p, pn, pi4, ((const float4*)gb)[j], gcb[j], gnm[j], gar[j],
                     clsval[(size_t)glab[j] * NP + row], cc, iou);
            float val = inflate(cc, k);
            if (lexless(val, j, best, bj)) { best = val; bj = j; }
        }
        rv[tid] = best; ri[tid] = bj; __syncthreads();
        for (int w = 128; w > 0; w >>= 1) {
            if (tid < w) {
                float ov = rv[tid + w]; int oi = ri[tid + w];
                if (lexless(ov, oi, rv[tid], ri[tid])) { rv[tid] = ov; ri[tid] = oi; }
            }
            __syncthreads();
        }
        if (tid == 0) {
            int nb = ri[0];
            int oldc = priorcol[row];
            if (nb != oldc) {
                atomicSub(&colsum[oldc], 1);
                atomicAdd(&colsum[nb], 1);
                priorcol[row] = nb;
            }
        }
        __syncthreads();
    }
}

// ---------------------------------------------------------------------------
// Final: fg = rowcnt>0; matched = priorcol (prior rows) else rowfirst. int32.
// ---------------------------------------------------------------------------
__global__ __launch_bounds__(256) void k_final(const int* __restrict__ rowcnt,
        const int* __restrict__ prior, const int* __restrict__ priorcol,
        const int* __restrict__ rowfirst, int* __restrict__ out)
{
    int i = blockIdx.x * 256 + threadIdx.x;
    if (i >= NP) return;
    int fg = rowcnt[i] > 0;
    out[i] = fg ? 1 : 0;
    out[NP + i] = fg ? (prior[i] ? priorcol[i] : rowfirst[i]) : 0;
}

extern "C" void kernel_launch(void* const* d_in, const int* in_sizes, int n_in,
                              void* d_out, int out_size, void* d_ws, size_t ws_size,
                              hipStream_t stream)
{
    (void)in_sizes; (void)n_in; (void)out_size; (void)ws_size;
    const float* logits = (const float*)d_in[0];
    const float* pboxes = (const float*)d_in[1];
    const float* gboxes = (const float*)d_in[2];
    const int*   glab   = (const int*)d_in[3];
    const int*   imgh   = (const int*)d_in[4];
    const int*   imgw   = (const int*)d_in[5];
    int* out = (int*)d_out;

    char* w = (char*)d_ws;
    float*  clsval  = (float*)(w);                    // 3,200,000
    float4* pnorm   = (float4*)(w + 3200000);         //   160,000
    float4* pinfo   = (float4*)(w + 3360000);         //   160,000
    float4* gcb     = (float4*)(w + 3520000);         //    16,000
    float4* gnm     = (float4*)(w + 3536000);         //    16,000
    float*  gar     = (float*)(w + 3552000);          //     4,000
    int* rowcnt     = (int*)(w + 3556000);            //    40,000
    int* rowfirst   = (int*)(w + 3596000);            //    40,000
    int* rowiter    = (int*)(w + 3636000);            //    40,000
    int* prior      = (int*)(w + 3676000);            //    40,000
    int* priorcol   = (int*)(w + 3716000);            //    40,000
    int* top5       = (int*)(w + 3756000);            //    20,000
    int* dkarr      = (int*)(w + 3776000);            //     4,000
    int* colsum     = (int*)(w + 3780000);            //     4,000
    int* scal       = (int*)(w + 3784000);            //       128
    unsigned long long* pck = (unsigned long long*)(w + 3784128); // 160,000
    float* piv      = (float*)(w + 3944128);          //    80,000

    hipLaunchKernelGGL(k_prep, dim3(2701), dim3(256), 0, stream,
                       logits, pboxes, gboxes, imgw, imgh,
                       clsval, pnorm, pinfo, gcb, gnm, gar,
                       rowcnt, rowfirst, rowiter, prior, priorcol, colsum, scal);
    hipLaunchKernelGGL(k_cost2, dim3(NG * NCH), dim3(256), 0, stream,
                       pboxes, gboxes, glab, clsval, pnorm, pinfo, gcb, gnm, gar,
                       pck, piv);
    hipLaunchKernelGGL(k_costmerge, dim3(4), dim3(256), 0, stream,
                       pck, piv, rowcnt, rowfirst, rowiter, top5, dkarr);
    hipLaunchKernelGGL(k_pfixsurv, dim3(2504), dim3(256), 0, stream,
                       pboxes, gboxes, glab, clsval, pnorm, pinfo, gcb, gnm, gar,
                       prior, priorcol, colsum, rowcnt, top5, dkarr);
    for (int t = 0; t < LMAX; t++) {
        hipLaunchKernelGGL(k_iterB, dim3(NG), dim3(256), 0, stream,
                           pboxes, gboxes, glab, clsval, pnorm, pinfo, gcb, gnm, gar,
                           top5, rowiter, rowcnt, rowfirst, colsum, scal, t);
        hipLaunchKernelGGL(k_iterC, dim3(2500), dim3(256), 0, stream,
                           pboxes, gboxes, glab, clsval, pnorm, pinfo, gcb, gnm, gar,
                           prior, rowiter, priorcol, colsum, scal, t);
    }
    hipLaunchKernelGGL(k_final, dim3(40), dim3(256), 0, stream,
                       rowcnt, prior, priorcol, rowfirst, out);
}